// Round 9
// baseline (370.179 us; speedup 1.0000x reference)
//
#include <hip/hip_runtime.h>

typedef unsigned short u16;
typedef __bf16 bf16x8 __attribute__((ext_vector_type(8)));
typedef float f32x4 __attribute__((ext_vector_type(4)));

__device__ inline float bf2f(u16 u) {
    unsigned int x = ((unsigned int)u) << 16;
    return __builtin_bit_cast(float, x);
}
__device__ inline u16 f2bf(float f) {
    unsigned int x = __builtin_bit_cast(unsigned int, f);
    return (u16)((x + 0x7FFFu + ((x >> 16) & 1u)) >> 16);
}
__device__ inline float sigm(float v) { return 1.f / (1.f + __expf(-v)); }

// pack 8 fp32 -> 8 bf16 (RNE) in a uint4
__device__ inline uint4 pack8(const float* p) {
    const float4* q = (const float4*)p;
    float4 a = q[0], b = q[1];
    union { u16 h[8]; uint4 v; } u;
    u.h[0] = f2bf(a.x); u.h[1] = f2bf(a.y); u.h[2] = f2bf(a.z); u.h[3] = f2bf(a.w);
    u.h[4] = f2bf(b.x); u.h[5] = f2bf(b.y); u.h[6] = f2bf(b.z); u.h[7] = f2bf(b.w);
    return u.v;
}

// async global->LDS DMA, 16 B per lane; lptr must be wave-uniform base.
typedef __attribute__((address_space(1))) unsigned int gu32;
typedef __attribute__((address_space(3))) unsigned int lu32;
__device__ inline void dma16(const u16* g, u16* l) {
    __builtin_amdgcn_global_load_lds((const gu32*)g, (lu32*)l, 16, 0, 0);
}

// ---------------------------------------------------------------------------
// fp32 -> bf16 conversion kernels
// ---------------------------------------------------------------------------
__global__ __launch_bounds__(256)
void cvt_bf16(const float* __restrict__ in, u16* __restrict__ out)
{
    int i = blockIdx.x * 256 + threadIdx.x;
    ((uint4*)out)[i] = pack8(in + (size_t)i * 8);
}
// 96x2048 -> 128x2048 zero-padded
__global__ __launch_bounds__(256)
void cvt_pad_xproj(const float* __restrict__ in, u16* __restrict__ out)
{
    int i = blockIdx.x * 256 + threadIdx.x;     // 32768 chunks of 8
    int row = (i * 8) >> 11;
    ((uint4*)out)[i] = (row < 96) ? pack8(in + (size_t)row * 2048 + ((i * 8) & 2047))
                                  : make_uint4(0u, 0u, 0u, 0u);
}

// ---------------------------------------------------------------------------
// m97-style MFMA NT GEMM: C = A[M,K]*B[N,K]^T, bf16 operands, fp32 acc.
// Chunk-linear LDS: chunk c (16B) = rows c%BM, kcols (c/BM)*8.., at offset c*16
// (satisfies global_load_lds wave-uniform-base + lane*16 constraint).
// BK=32. Split-K via blockIdx.z: k window [z*ksplit, (z+1)*ksplit), output
// at Cout + z*zStride. EPI: 0 none; 1 softplus(acc+bias); 2 silu cols>=2048.
// ---------------------------------------------------------------------------
template<int BM, int BN, int EPI, bool OUTF32>
__global__ __launch_bounds__(256, 2)
void gemm_dma(const u16* __restrict__ A, int lda,
              const u16* __restrict__ B, int ldb,
              void* __restrict__ Cout, int ldc,
              int N, int ksplit, size_t zStride,
              const float* __restrict__ bias)
{
    constexpr int MI = BM / 32, NJ = BN / 32;
    constexpr int ISSA = (BM * 4) / 256;
    constexpr int ISSB = (BN * 4) / 256;
    __shared__ u16 sA[BM * 32];
    __shared__ u16 sB[BN * 32];

    const int tid  = threadIdx.x;
    const int lane = tid & 63;
    const int wave = tid >> 6;
    const int wm = (wave >> 1) * (BM / 2);
    const int wn = (wave & 1) * (BN / 2);
    const int m0 = blockIdx.y * BM;
    const int n0 = blockIdx.x * BN;
    const int lm = lane & 15;
    const int qsel = lane >> 4;
    const int k0 = blockIdx.z * ksplit;

    const u16* ga[ISSA];
    const u16* gb[ISSB];
    #pragma unroll
    for (int s = 0; s < ISSA; ++s) {
        int c = s * 256 + tid;
        ga[s] = A + (size_t)(m0 + (c % BM)) * lda + k0 + (c / BM) * 8;
    }
    #pragma unroll
    for (int s = 0; s < ISSB; ++s) {
        int c = s * 256 + tid;
        gb[s] = B + (size_t)(n0 + (c % BN)) * ldb + k0 + (c / BN) * 8;
    }

    f32x4 acc[MI][NJ] = {};

    for (int kb = 0; kb < ksplit; kb += 32) {
        #pragma unroll
        for (int s = 0; s < ISSA; ++s)
            dma16(ga[s], sA + (s * 256 + wave * 64) * 8);
        #pragma unroll
        for (int s = 0; s < ISSB; ++s)
            dma16(gb[s], sB + (s * 256 + wave * 64) * 8);
        #pragma unroll
        for (int s = 0; s < ISSA; ++s) ga[s] += 32;
        #pragma unroll
        for (int s = 0; s < ISSB; ++s) gb[s] += 32;
        __syncthreads();

        bf16x8 af[MI], bfr[NJ];
        #pragma unroll
        for (int i = 0; i < MI; ++i)
            af[i] = *(const bf16x8*)&sA[(qsel * BM + wm + i * 16 + lm) * 8];
        #pragma unroll
        for (int j = 0; j < NJ; ++j)
            bfr[j] = *(const bf16x8*)&sB[(qsel * BN + wn + j * 16 + lm) * 8];
        #pragma unroll
        for (int i = 0; i < MI; ++i)
            #pragma unroll
            for (int j = 0; j < NJ; ++j)
                acc[i][j] = __builtin_amdgcn_mfma_f32_16x16x32_bf16(af[i], bfr[j], acc[i][j], 0, 0, 0);
        __syncthreads();
    }

    // C/D layout: col = lane&15, row = (lane>>4)*4 + reg  [m89/m91-verified]
    char* cbase = (char*)Cout + (size_t)blockIdx.z * zStride;
    #pragma unroll
    for (int i = 0; i < MI; ++i) {
        int crow = m0 + wm + i * 16 + ((lane >> 4) << 2);
        #pragma unroll
        for (int j = 0; j < NJ; ++j) {
            int ccol = n0 + wn + j * 16 + lm;
            if (ccol < N) {
                #pragma unroll
                for (int r = 0; r < 4; ++r) {
                    float v = acc[i][j][r];
                    if (EPI == 1) { v += bias[ccol]; v = (v > 20.f) ? v : log1pf(__expf(v)); }
                    if (EPI == 2 && ccol >= 2048) v *= sigm(v);
                    size_t off = (size_t)(crow + r) * ldc + ccol;
                    if (OUTF32) ((float*)cbase)[off] = v;
                    else        ((u16*)cbase)[off]   = f2bf(v);
                }
            }
        }
    }
}

__global__ __launch_bounds__(256)
void reduce96(const float* __restrict__ splits, u16* __restrict__ xdbl)
{
    int i = blockIdx.x * 256 + threadIdx.x;   // < 196608
    float acc = 0.f;
    #pragma unroll
    for (int z = 0; z < 8; ++z) acc += splits[(size_t)z * 196608 + i];
    xdbl[i] = f2bf(acc);
}

// ---------------------------------------------------------------------------
// Causal depthwise conv1d (k=4) + bias + SiLU on xr cols [0,2048) -> xs bf16.
// ---------------------------------------------------------------------------
__global__ __launch_bounds__(256)
void conv_silu(const u16* __restrict__ xr, const float* __restrict__ w,
               const float* __restrict__ bias, u16* __restrict__ xs)
{
    int idx = blockIdx.x * 256 + threadIdx.x;
    int d = idx & 2047, t = (idx >> 11) & 1023, b = idx >> 21;
    const u16* base = xr + (size_t)b * 1024 * 4096;
    float acc = bias[d];
    #pragma unroll
    for (int j = 0; j < 4; ++j) {
        int ti = t - 3 + j;
        if (ti >= 0) acc = fmaf(w[d * 4 + j], bf2f(base[(size_t)ti * 4096 + d]), acc);
    }
    xs[idx] = f2bf(acc * sigm(acc));
}

// ---------------------------------------------------------------------------
// Chunked parallel scan (R8-validated). Thread = one d, h[16] in registers.
// ---------------------------------------------------------------------------
template<int PHC>
__global__ __launch_bounds__(256)
void scan_chunk(const u16* __restrict__ deltag, u16* __restrict__ xsg,
                const u16* __restrict__ xdbl, const float* __restrict__ A_log,
                const u16* __restrict__ xr, float* __restrict__ summ,
                float* __restrict__ ssum)
{
    const int tid = threadIdx.x;
    const int d0 = blockIdx.x * 256;
    const int c  = blockIdx.y;
    const int b  = blockIdx.z;
    const int d  = d0 + tid;
    const int tok0 = b * 1024 + c * 32;

    __shared__ u16 s_del[32][256];
    __shared__ u16 s_uu[32][256];
    __shared__ u16 s_bc[32][32];
    __shared__ u16 s_res[PHC ? 32 : 1][PHC ? 256 : 1];
    __shared__ u16 s_y[PHC ? 32 : 1][PHC ? 256 : 1];

    for (int i = tid; i < 1024; i += 256) {
        int tl = i >> 5, v = i & 31;
        size_t tok = (size_t)(tok0 + tl);
        *(uint4*)&s_del[tl][v * 8] = *(const uint4*)&deltag[tok * 4096 + d0 + v * 8];
        *(uint4*)&s_uu[tl][v * 8]  = *(const uint4*)&xsg[tok * 2048 + d0 + v * 8];
        if (PHC)
            *(uint4*)&s_res[tl][v * 8] = *(const uint4*)&xr[tok * 4096 + 2048 + d0 + v * 8];
    }
    for (int i = tid; i < 1024; i += 256) {
        int tl = i >> 5, j = i & 31;
        s_bc[tl][j] = xdbl[(size_t)(tok0 + tl) * 96 + 64 + j];
    }

    float Ar[16], h[16];
    {
        const float4* Ap = (const float4*)(A_log + (size_t)d * 16);
        #pragma unroll
        for (int q = 0; q < 4; ++q) {
            float4 a = Ap[q];
            Ar[q * 4 + 0] = -__expf(a.x); Ar[q * 4 + 1] = -__expf(a.y);
            Ar[q * 4 + 2] = -__expf(a.z); Ar[q * 4 + 3] = -__expf(a.w);
        }
    }
    if (PHC) {
        const float4* hp = (const float4*)&summ[((size_t)(b * 32 + c) * 2048 + d) * 16];
        #pragma unroll
        for (int q = 0; q < 4; ++q) {
            float4 v = hp[q];
            h[q * 4 + 0] = v.x; h[q * 4 + 1] = v.y; h[q * 4 + 2] = v.z; h[q * 4 + 3] = v.w;
        }
    } else {
        #pragma unroll
        for (int n = 0; n < 16; ++n) h[n] = 0.f;
    }
    __syncthreads();

    float S = 0.f;
    #pragma unroll 4
    for (int tl = 0; tl < 32; ++tl) {
        float dlt = bf2f(s_del[tl][tid]);
        float du = dlt * bf2f(s_uu[tl][tid]);
        if (!PHC) S += dlt;
        #pragma unroll
        for (int n = 0; n < 16; ++n)
            h[n] = fmaf(__expf(dlt * Ar[n]), h[n], du * bf2f(s_bc[tl][n]));
        if (PHC) {
            float y = 0.f;
            #pragma unroll
            for (int n = 0; n < 16; ++n)
                y = fmaf(h[n], bf2f(s_bc[tl][16 + n]), y);
            s_y[tl][tid] = f2bf(y * bf2f(s_res[tl][tid]));
        }
    }

    if (!PHC) {
        float4* bp = (float4*)&summ[((size_t)(b * 32 + c) * 2048 + d) * 16];
        #pragma unroll
        for (int q = 0; q < 4; ++q)
            bp[q] = make_float4(h[q * 4], h[q * 4 + 1], h[q * 4 + 2], h[q * 4 + 3]);
        ssum[(size_t)(b * 32 + c) * 2048 + d] = S;
    } else {
        __syncthreads();
        for (int i = tid; i < 1024; i += 256) {
            int tl = i >> 5, v = i & 31;
            *(uint4*)&xsg[(size_t)(tok0 + tl) * 2048 + d0 + v * 8] = *(uint4*)&s_y[tl][v * 8];
        }
    }
}

__global__ __launch_bounds__(256)
void scan_phaseB(float* __restrict__ summ, const float* __restrict__ ssum,
                 const float* __restrict__ A_log)
{
    int g = blockIdx.x * 256 + threadIdx.x;
    int n = g & 15;
    int d = (g >> 4) & 2047;
    int b = g >> 15;
    float An = -__expf(A_log[(size_t)d * 16 + n]);
    float h = 0.f;
    for (int c = 0; c < 32; ++c) {
        size_t idx = ((size_t)(b * 32 + c) * 2048 + d) * 16 + n;
        float bc = summ[idx];
        float Sc = ssum[(size_t)(b * 32 + c) * 2048 + d];
        summ[idx] = h;
        h = fmaf(__expf(An * Sc), h, bc);
    }
}

__global__ void sentinel_kernel(float* out, float v) { out[0] = v; }

// ---------------------------------------------------------------------------
extern "C" void kernel_launch(void* const* d_in, const int* in_sizes, int n_in,
                              void* d_out, int out_size, void* d_ws, size_t ws_size,
                              hipStream_t stream)
{
    const float* x         = (const float*)d_in[0];
    const float* in_w      = (const float*)d_in[1];
    const float* conv_w    = (const float*)d_in[2];
    const float* conv_b    = (const float*)d_in[3];
    const float* xproj_w   = (const float*)d_in[4];
    const float* dtproj_w  = (const float*)d_in[5];
    const float* dtproj_b  = (const float*)d_in[6];
    const float* A_log     = (const float*)d_in[7];
    const float* outproj_w = (const float*)d_in[8];
    float* out = (float*)d_out;

    static const int EXP[9] = {2097152, 4194304, 8192, 2048, 196608, 131072, 2048, 32768, 2097152};
    int bad = -1;
    if (n_in != 9) bad = 9;
    else { for (int i = 0; i < 9; ++i) if (in_sizes[i] != EXP[i]) { bad = i; break; } }
    if (bad < 0 && out_size != 2097152) bad = 10;
    if (bad < 0 && ws_size < 34734080u) bad = 11;    // high-water mark
    if (bad >= 0) {
        sentinel_kernel<<<1, 1, 0, stream>>>(out, 131072.f * (1.f + (float)bad / 16.f));
        return;
    }

    // ws map: xr 16.78M | xs 8.39M | xdbl 0.39M | region R (10.3M, phased)
    char* ws = (char*)d_ws;
    u16*   xr     = (u16*)(ws);               // [2048][4096] cols<2048: xs_pre->delta; >=2048: silu(res)
    u16*   xs     = (u16*)(ws + 16777216);    // [2048][2048] x_bf -> u -> yg
    u16*   xdbl   = (u16*)(ws + 25165824);    // [2048][96]
    char*  R      = ws + 25559040;
    u16*   x_bf   = xs;                       // borrow xs region pre-conv
    u16*   inw_bf = (u16*)(R);                // 8.39M  (phase 1)
    u16*   xpw_bf = (u16*)(R + 8388608);      // 0.52M padded 128x2048
    u16*   dtw_bf = (u16*)(R + 8912896);      // 0.26M
    float* splits = (float*)(R);              // 6.29M  (phase 2, inw dead)
    float* summ   = (float*)(R);              // 8.39M  (phase 3, splits dead)
    float* ssum   = (float*)(R + 8388608);    // 0.52M  (xpw dead)
    u16*   opw_bf = (u16*)(R);                // 4.19M  (phase 4, summ dead)

    // 0) conversions
    cvt_bf16<<<1024, 256, 0, stream>>>(x, x_bf);
    cvt_bf16<<<2048, 256, 0, stream>>>(in_w, inw_bf);
    cvt_pad_xproj<<<128, 256, 0, stream>>>(xproj_w, xpw_bf);
    cvt_bf16<<<64, 256, 0, stream>>>(dtproj_w, dtw_bf);
    // 1) in_proj (+silu on res half): 2048x4096, K=1024
    gemm_dma<128, 128, 2, false><<<dim3(32, 16, 1), 256, 0, stream>>>(
        x_bf, 1024, inw_bf, 1024, xr, 4096, 4096, 1024, 0, nullptr);
    // 2) conv + silu -> xs (overwrites x_bf; after GEMM1)
    conv_silu<<<16384, 256, 0, stream>>>(xr, conv_w, conv_b, xs);
    // 3) x_proj split-K=8 -> splits -> reduce -> xdbl
    gemm_dma<128, 128, 0, true><<<dim3(1, 16, 8), 256, 0, stream>>>(
        xs, 2048, xpw_bf, 2048, splits, 96, 96, 256, 786432, nullptr);
    reduce96<<<768, 256, 0, stream>>>(splits, xdbl);
    // 4) delta = softplus(xdbl[:,:64] @ dtw^T + b) -> xr cols [0,2048)
    gemm_dma<128, 128, 1, false><<<dim3(16, 16, 1), 256, 0, stream>>>(
        xdbl, 96, dtw_bf, 64, xr, 4096, 2048, 64, 0, dtproj_b);
    // 5) chunked scan A -> B -> C (yg in-place over xs)
    scan_chunk<0><<<dim3(8, 32, 2), 256, 0, stream>>>(xr, xs, xdbl, A_log, xr, summ, ssum);
    scan_phaseB<<<256, 256, 0, stream>>>(summ, ssum, A_log);
    scan_chunk<1><<<dim3(8, 32, 2), 256, 0, stream>>>(xr, xs, xdbl, A_log, xr, summ, ssum);
    // 6) out_proj 64x64 tiles (512 blocks): 2048x1024, K=2048 -> fp32 d_out
    cvt_bf16<<<1024, 256, 0, stream>>>(outproj_w, opw_bf);
    gemm_dma<64, 64, 0, true><<<dim3(16, 32, 1), 256, 0, stream>>>(
        xs, 2048, opw_bf, 2048, out, 1024, 1024, 2048, 0, nullptr);
}

// Round 10
// 262.622 us; speedup vs baseline: 1.4096x; 1.4096x over previous
//
#include <hip/hip_runtime.h>

typedef unsigned short u16;
typedef __bf16 bf16x8 __attribute__((ext_vector_type(8)));
typedef float f32x4 __attribute__((ext_vector_type(4)));

__device__ inline float bf2f(u16 u) {
    unsigned int x = ((unsigned int)u) << 16;
    return __builtin_bit_cast(float, x);
}
__device__ inline u16 f2bf(float f) {
    unsigned int x = __builtin_bit_cast(unsigned int, f);
    return (u16)((x + 0x7FFFu + ((x >> 16) & 1u)) >> 16);
}
__device__ inline float sigm(float v) { return 1.f / (1.f + __expf(-v)); }

__device__ inline uint4 pack8(const float* p) {
    const float4* q = (const float4*)p;
    float4 a = q[0], b = q[1];
    union { u16 h[8]; uint4 v; } u;
    u.h[0] = f2bf(a.x); u.h[1] = f2bf(a.y); u.h[2] = f2bf(a.z); u.h[3] = f2bf(a.w);
    u.h[4] = f2bf(b.x); u.h[5] = f2bf(b.y); u.h[6] = f2bf(b.z); u.h[7] = f2bf(b.w);
    return u.v;
}

// ---------------------------------------------------------------------------
// fp32 -> bf16 conversion kernels
// ---------------------------------------------------------------------------
__global__ __launch_bounds__(256)
void cvt_bf16(const float* __restrict__ in, u16* __restrict__ out)
{
    int i = blockIdx.x * 256 + threadIdx.x;
    ((uint4*)out)[i] = pack8(in + (size_t)i * 8);
}
// 96x2048 -> 128x2048 zero-padded (kills B-row guards in xproj GEMM)
__global__ __launch_bounds__(256)
void cvt_pad_xproj(const float* __restrict__ in, u16* __restrict__ out)
{
    int i = blockIdx.x * 256 + threadIdx.x;
    int row = (i * 8) >> 11;
    ((uint4*)out)[i] = (row < 96) ? pack8(in + (size_t)row * 2048 + ((i * 8) & 2047))
                                  : make_uint4(0u, 0u, 0u, 0u);
}

// ---------------------------------------------------------------------------
// MFMA NT GEMM, register-prefetch double-buffered. bf16 operands (B rows must
// cover full BN; pad upstream). C = A[M,K]*B[N,K]^T over k window
// [z*ksplit,(z+1)*ksplit), output at C + z*zElems elements.
// 128x128 tile, BK=32, 4 waves x (64x64). Lanes cover 64B K-runs (coalesced).
// EPI: 0 none; 1 softplus(acc+bias[col]); 2 silu on cols>=2048.
// OUTF32: fp32 vs bf16 element type of C.
// ---------------------------------------------------------------------------
template<int EPI, bool OUTF32>
__global__ __launch_bounds__(256, 2)
void gemm2(const u16* __restrict__ A, int lda,
           const u16* __restrict__ B, int ldb,
           void* __restrict__ Cout, int ldc,
           int N, int ksplit, size_t zElems,
           const float* __restrict__ bias)
{
    __shared__ u16 sA[128][40];   // +8 pad: lanes 0-7 tile all 32 banks, 2-way free
    __shared__ u16 sB[128][40];

    const int tid  = threadIdx.x;
    const int lane = tid & 63;
    const int wave = tid >> 6;
    const int wm = (wave >> 1) * 64;
    const int wn = (wave & 1) * 64;
    const int m0 = blockIdx.y * 128;
    const int n0 = blockIdx.x * 128;
    const int lm = lane & 15;
    const int kq = (lane >> 4) * 8;
    const int k0 = blockIdx.z * ksplit;

    // chunk c -> row c>>2, kcols (c&3)*8.. : consecutive lanes = 64B K-runs
    const int r0 = tid >> 2, q0 = (tid & 3) * 8;
    const int r1 = (tid + 256) >> 2, q1 = ((tid + 256) & 3) * 8;
    const u16* gA0 = A + (size_t)(m0 + r0) * lda + k0 + q0;
    const u16* gA1 = A + (size_t)(m0 + r1) * lda + k0 + q1;
    const u16* gB0 = B + (size_t)(n0 + r0) * ldb + k0 + q0;
    const u16* gB1 = B + (size_t)(n0 + r1) * ldb + k0 + q1;

    f32x4 acc[4][4] = {};

    // prologue: prefetch tile 0 into registers
    uint4 pa0 = *(const uint4*)gA0, pa1 = *(const uint4*)gA1;
    uint4 pb0 = *(const uint4*)gB0, pb1 = *(const uint4*)gB1;

    for (int kb = 0; kb < ksplit; kb += 32) {
        *(uint4*)&sA[r0][q0] = pa0;
        *(uint4*)&sA[r1][q1] = pa1;
        *(uint4*)&sB[r0][q0] = pb0;
        *(uint4*)&sB[r1][q1] = pb1;
        __syncthreads();

        // prefetch next tile while MFMAs below consume this one
        if (kb + 32 < ksplit) {
            pa0 = *(const uint4*)(gA0 + kb + 32);
            pa1 = *(const uint4*)(gA1 + kb + 32);
            pb0 = *(const uint4*)(gB0 + kb + 32);
            pb1 = *(const uint4*)(gB1 + kb + 32);
        }

        bf16x8 af[4], bfr[4];
        #pragma unroll
        for (int i = 0; i < 4; ++i)
            af[i] = *(const bf16x8*)&sA[wm + i * 16 + lm][kq];
        #pragma unroll
        for (int j = 0; j < 4; ++j)
            bfr[j] = *(const bf16x8*)&sB[wn + j * 16 + lm][kq];
        #pragma unroll
        for (int i = 0; i < 4; ++i)
            #pragma unroll
            for (int j = 0; j < 4; ++j)
                acc[i][j] = __builtin_amdgcn_mfma_f32_16x16x32_bf16(af[i], bfr[j], acc[i][j], 0, 0, 0);
        __syncthreads();
    }

    // C/D layout: col = lane&15, row = (lane>>4)*4 + reg  [m89/m91-verified]
    #pragma unroll
    for (int i = 0; i < 4; ++i) {
        int crow = m0 + wm + i * 16 + ((lane >> 4) << 2);
        #pragma unroll
        for (int j = 0; j < 4; ++j) {
            int ccol = n0 + wn + j * 16 + lm;
            if (ccol < N) {
                #pragma unroll
                for (int r = 0; r < 4; ++r) {
                    float v = acc[i][j][r];
                    if (EPI == 1) { v += bias[ccol]; v = (v > 20.f) ? v : log1pf(__expf(v)); }
                    if (EPI == 2 && ccol >= 2048) v *= sigm(v);
                    size_t off = (size_t)blockIdx.z * zElems + (size_t)(crow + r) * ldc + ccol;
                    if (OUTF32) ((float*)Cout)[off] = v;
                    else        ((u16*)Cout)[off]   = f2bf(v);
                }
            }
        }
    }
}

// xproj split reduce: 8 fp32 partials -> bf16
__global__ __launch_bounds__(256)
void reduce96(const float* __restrict__ splits, u16* __restrict__ xdbl)
{
    int i = blockIdx.x * 256 + threadIdx.x;   // < 196608
    float acc = 0.f;
    #pragma unroll
    for (int z = 0; z < 8; ++z) acc += splits[(size_t)z * 196608 + i];
    xdbl[i] = f2bf(acc);
}

// out_proj split reduce: 4 bf16 partials -> fp32 d_out (8 elems/thread)
__global__ __launch_bounds__(256)
void reduce_out(const u16* __restrict__ parts, float* __restrict__ out)
{
    int i = blockIdx.x * 256 + threadIdx.x;   // chunk of 8; grid 1024
    float acc[8] = {};
    #pragma unroll
    for (int z = 0; z < 4; ++z) {
        uint4 v = ((const uint4*)(parts + (size_t)z * 2097152))[i];
        const u16* h = (const u16*)&v;
        #pragma unroll
        for (int e = 0; e < 8; ++e) acc[e] += bf2f(h[e]);
    }
    float4* o = (float4*)(out + (size_t)i * 8);
    o[0] = make_float4(acc[0], acc[1], acc[2], acc[3]);
    o[1] = make_float4(acc[4], acc[5], acc[6], acc[7]);
}

// ---------------------------------------------------------------------------
// Causal depthwise conv1d (k=4) + bias + SiLU on xr cols [0,2048) -> xs bf16.
// ---------------------------------------------------------------------------
__global__ __launch_bounds__(256)
void conv_silu(const u16* __restrict__ xr, const float* __restrict__ w,
               const float* __restrict__ bias, u16* __restrict__ xs)
{
    int idx = blockIdx.x * 256 + threadIdx.x;
    int d = idx & 2047, t = (idx >> 11) & 1023, b = idx >> 21;
    const u16* base = xr + (size_t)b * 1024 * 4096;
    float acc = bias[d];
    #pragma unroll
    for (int j = 0; j < 4; ++j) {
        int ti = t - 3 + j;
        if (ti >= 0) acc = fmaf(w[d * 4 + j], bf2f(base[(size_t)ti * 4096 + d]), acc);
    }
    xs[idx] = f2bf(acc * sigm(acc));
}

// ---------------------------------------------------------------------------
// Chunked parallel scan (R8-validated). Thread = one d, h[16] in registers.
// ---------------------------------------------------------------------------
template<int PHC>
__global__ __launch_bounds__(256)
void scan_chunk(const u16* __restrict__ deltag, u16* __restrict__ xsg,
                const u16* __restrict__ xdbl, const float* __restrict__ A_log,
                const u16* __restrict__ xr, float* __restrict__ summ,
                float* __restrict__ ssum)
{
    const int tid = threadIdx.x;
    const int d0 = blockIdx.x * 256;
    const int c  = blockIdx.y;
    const int b  = blockIdx.z;
    const int d  = d0 + tid;
    const int tok0 = b * 1024 + c * 32;

    __shared__ u16 s_del[32][256];
    __shared__ u16 s_uu[32][256];
    __shared__ u16 s_bc[32][32];
    __shared__ u16 s_res[PHC ? 32 : 1][PHC ? 256 : 1];
    __shared__ u16 s_y[PHC ? 32 : 1][PHC ? 256 : 1];

    for (int i = tid; i < 1024; i += 256) {
        int tl = i >> 5, v = i & 31;
        size_t tok = (size_t)(tok0 + tl);
        *(uint4*)&s_del[tl][v * 8] = *(const uint4*)&deltag[tok * 4096 + d0 + v * 8];
        *(uint4*)&s_uu[tl][v * 8]  = *(const uint4*)&xsg[tok * 2048 + d0 + v * 8];
        if (PHC)
            *(uint4*)&s_res[tl][v * 8] = *(const uint4*)&xr[tok * 4096 + 2048 + d0 + v * 8];
    }
    for (int i = tid; i < 1024; i += 256) {
        int tl = i >> 5, j = i & 31;
        s_bc[tl][j] = xdbl[(size_t)(tok0 + tl) * 96 + 64 + j];
    }

    float Ar[16], h[16];
    {
        const float4* Ap = (const float4*)(A_log + (size_t)d * 16);
        #pragma unroll
        for (int q = 0; q < 4; ++q) {
            float4 a = Ap[q];
            Ar[q * 4 + 0] = -__expf(a.x); Ar[q * 4 + 1] = -__expf(a.y);
            Ar[q * 4 + 2] = -__expf(a.z); Ar[q * 4 + 3] = -__expf(a.w);
        }
    }
    if (PHC) {
        const float4* hp = (const float4*)&summ[((size_t)(b * 32 + c) * 2048 + d) * 16];
        #pragma unroll
        for (int q = 0; q < 4; ++q) {
            float4 v = hp[q];
            h[q * 4 + 0] = v.x; h[q * 4 + 1] = v.y; h[q * 4 + 2] = v.z; h[q * 4 + 3] = v.w;
        }
    } else {
        #pragma unroll
        for (int n = 0; n < 16; ++n) h[n] = 0.f;
    }
    __syncthreads();

    float S = 0.f;
    #pragma unroll 4
    for (int tl = 0; tl < 32; ++tl) {
        float dlt = bf2f(s_del[tl][tid]);
        float du = dlt * bf2f(s_uu[tl][tid]);
        if (!PHC) S += dlt;
        #pragma unroll
        for (int n = 0; n < 16; ++n)
            h[n] = fmaf(__expf(dlt * Ar[n]), h[n], du * bf2f(s_bc[tl][n]));
        if (PHC) {
            float y = 0.f;
            #pragma unroll
            for (int n = 0; n < 16; ++n)
                y = fmaf(h[n], bf2f(s_bc[tl][16 + n]), y);
            s_y[tl][tid] = f2bf(y * bf2f(s_res[tl][tid]));
        }
    }

    if (!PHC) {
        float4* bp = (float4*)&summ[((size_t)(b * 32 + c) * 2048 + d) * 16];
        #pragma unroll
        for (int q = 0; q < 4; ++q)
            bp[q] = make_float4(h[q * 4], h[q * 4 + 1], h[q * 4 + 2], h[q * 4 + 3]);
        ssum[(size_t)(b * 32 + c) * 2048 + d] = S;
    } else {
        __syncthreads();
        for (int i = tid; i < 1024; i += 256) {
            int tl = i >> 5, v = i & 31;
            *(uint4*)&xsg[(size_t)(tok0 + tl) * 2048 + d0 + v * 8] = *(uint4*)&s_y[tl][v * 8];
        }
    }
}

__global__ __launch_bounds__(256)
void scan_phaseB(float* __restrict__ summ, const float* __restrict__ ssum,
                 const float* __restrict__ A_log)
{
    int g = blockIdx.x * 256 + threadIdx.x;
    int n = g & 15;
    int d = (g >> 4) & 2047;
    int b = g >> 15;
    float An = -__expf(A_log[(size_t)d * 16 + n]);
    float h = 0.f;
    for (int c = 0; c < 32; ++c) {
        size_t idx = ((size_t)(b * 32 + c) * 2048 + d) * 16 + n;
        float bc = summ[idx];
        float Sc = ssum[(size_t)(b * 32 + c) * 2048 + d];
        summ[idx] = h;
        h = fmaf(__expf(An * Sc), h, bc);
    }
}

__global__ void sentinel_kernel(float* out, float v) { out[0] = v; }

// ---------------------------------------------------------------------------
extern "C" void kernel_launch(void* const* d_in, const int* in_sizes, int n_in,
                              void* d_out, int out_size, void* d_ws, size_t ws_size,
                              hipStream_t stream)
{
    const float* x         = (const float*)d_in[0];
    const float* in_w      = (const float*)d_in[1];
    const float* conv_w    = (const float*)d_in[2];
    const float* conv_b    = (const float*)d_in[3];
    const float* xproj_w   = (const float*)d_in[4];
    const float* dtproj_w  = (const float*)d_in[5];
    const float* dtproj_b  = (const float*)d_in[6];
    const float* A_log     = (const float*)d_in[7];
    const float* outproj_w = (const float*)d_in[8];
    float* out = (float*)d_out;

    static const int EXP[9] = {2097152, 4194304, 8192, 2048, 196608, 131072, 2048, 32768, 2097152};
    int bad = -1;
    if (n_in != 9) bad = 9;
    else { for (int i = 0; i < 9; ++i) if (in_sizes[i] != EXP[i]) { bad = i; break; } }
    if (bad < 0 && out_size != 2097152) bad = 10;
    if (bad < 0 && ws_size < 34734080u) bad = 11;
    if (bad >= 0) {
        sentinel_kernel<<<1, 1, 0, stream>>>(out, 131072.f * (1.f + (float)bad / 16.f));
        return;
    }

    // ws: xr 16.78M | xs 8.39M | xdbl 0.39M | region R 10.3M (phased)
    char* ws = (char*)d_ws;
    u16*   xr      = (u16*)(ws);              // [2048][4096] xs_pre->delta | silu(res); dead after scan -> out partials
    u16*   xs      = (u16*)(ws + 16777216);   // [2048][2048] x_bf -> u -> yg
    u16*   xdbl    = (u16*)(ws + 25165824);   // [2048][96]
    char*  R       = ws + 25559040;
    u16*   x_bf    = xs;                      // borrow xs pre-conv
    u16*   inw_bf  = (u16*)(R);               // 8.39M (phase 1)
    u16*   xpw_bf  = (u16*)(R + 8388608);     // 0.52M
    u16*   dtw_bf  = (u16*)(R + 8912896);     // 0.26M
    float* splits  = (float*)(R);             // 6.29M (phase 2, inw dead)
    float* summ    = (float*)(R);             // 8.39M (phase 3, splits dead)
    float* ssum    = (float*)(R + 8388608);   // 0.52M (xpw dead)
    u16*   opw_bf  = (u16*)(R);               // 4.19M (phase 4, summ dead)
    u16*   oparts  = xr;                      // 16.78M = 4 x [2048][1024] bf16 (xr dead)

    // 0) conversions
    cvt_bf16<<<1024, 256, 0, stream>>>(x, x_bf);
    cvt_bf16<<<2048, 256, 0, stream>>>(in_w, inw_bf);
    cvt_pad_xproj<<<128, 256, 0, stream>>>(xproj_w, xpw_bf);
    cvt_bf16<<<64, 256, 0, stream>>>(dtproj_w, dtw_bf);
    // 1) in_proj (+silu on res half): 2048x4096, K=1024
    gemm2<2, false><<<dim3(32, 16, 1), 256, 0, stream>>>(
        x_bf, 1024, inw_bf, 1024, xr, 4096, 4096, 1024, 0, nullptr);
    // 2) conv + silu -> xs (overwrites x_bf)
    conv_silu<<<16384, 256, 0, stream>>>(xr, conv_w, conv_b, xs);
    // 3) x_proj split-K=8 -> fp32 splits -> reduce -> xdbl
    gemm2<0, true><<<dim3(1, 16, 8), 256, 0, stream>>>(
        xs, 2048, xpw_bf, 2048, splits, 96, 96, 256, 196608, nullptr);
    reduce96<<<768, 256, 0, stream>>>(splits, xdbl);
    // 4) delta = softplus(xdbl[:,:64] @ dtw^T + b) -> xr cols [0,2048)
    gemm2<1, false><<<dim3(16, 16, 1), 256, 0, stream>>>(
        xdbl, 96, dtw_bf, 64, xr, 4096, 2048, 64, 0, dtproj_b);
    // 5) chunked scan A -> B -> C (yg in-place over xs)
    scan_chunk<0><<<dim3(8, 32, 2), 256, 0, stream>>>(xr, xs, xdbl, A_log, xr, summ, ssum);
    scan_phaseB<<<256, 256, 0, stream>>>(summ, ssum, A_log);
    scan_chunk<1><<<dim3(8, 32, 2), 256, 0, stream>>>(xr, xs, xdbl, A_log, xr, summ, ssum);
    // 6) out_proj split-K=4 (bf16 partials into dead xr) + reduce -> fp32 d_out
    cvt_bf16<<<1024, 256, 0, stream>>>(outproj_w, opw_bf);
    gemm2<0, false><<<dim3(8, 16, 4), 256, 0, stream>>>(
        xs, 2048, opw_bf, 2048, oparts, 1024, 1024, 512, 2097152, nullptr);
    reduce_out<<<1024, 256, 0, stream>>>(oparts, out);
}